// Round 12
// baseline (413.784 us; speedup 1.0000x reference)
//
#include <hip/hip_runtime.h>
#include <math.h>

// DirectionalConv, two-stage:
//   bin_kernel2: per-pixel packed (bf16(x)<<16 | q), branch-free bit-exact fdlibm binning
//   dirconv_mfma5: masked-K MFMA GEMM; A fragments global->REGISTERS (double-buffered,
//                  full-phase prefetch, imm-offset loads); B one-hot in LDS dbuf.
//                  LDS-read insts halved vs mfma4 -> MFMA pipe becomes critical.
// Fallback (small ws): proven fused kernel.

#define TH 8
#define TW 32

typedef __attribute__((ext_vector_type(8)))  short    short8;
typedef __attribute__((ext_vector_type(16))) float    f32x16;
typedef __attribute__((ext_vector_type(4)))  unsigned u32x4;

// ---------------- fdlibm float atan (glibc s_atanf.c), bit-exact port (branchy) ----------------
__device__ __forceinline__ float atanf_fdlibm(float x) {
#pragma clang fp contract(off)
    const float atanhi0 = 4.6364760399e-01f, atanhi1 = 7.8539812565e-01f,
                atanhi2 = 9.8279368877e-01f, atanhi3 = 1.5707962513e+00f;
    const float atanlo0 = 5.0121582440e-09f, atanlo1 = 3.7748947079e-08f,
                atanlo2 = 3.4473217170e-08f, atanlo3 = 7.5497894159e-08f;
    const float aT0 = 3.3333334327e-01f, aT1 = -2.0000000298e-01f, aT2 = 1.4285714924e-01f,
                aT3 = -1.1111110449e-01f, aT4 = 9.0908870101e-02f, aT5 = -7.6918758452e-02f,
                aT6 = 6.6610731184e-02f, aT7 = -5.8335702866e-02f, aT8 = 4.9768779427e-02f,
                aT9 = -3.6531571299e-02f, aT10 = 1.6285819933e-02f;

    int hx = __float_as_int(x);
    int ix = hx & 0x7fffffff;
    int id;
    if (ix >= 0x4c800000) {
        if (ix > 0x7f800000) return x + x;
        return (hx > 0) ? (atanhi3 + atanlo3) : (-atanhi3 - atanlo3);
    }
    if (ix < 0x3ee00000) {
        if (ix < 0x31000000) return x;
        id = -1;
    } else {
        x = fabsf(x);
        if (ix < 0x3f980000) {
            if (ix < 0x3f300000) { id = 0; x = (2.0f * x - 1.0f) / (2.0f + x); }
            else                 { id = 1; x = (x - 1.0f) / (x + 1.0f); }
        } else {
            if (ix < 0x401c0000) { id = 2; x = (x - 1.5f) / (1.0f + 1.5f * x); }
            else                 { id = 3; x = -1.0f / x; }
        }
    }
    float z = x * x;
    float w = z * z;
    float s1 = z * (aT0 + w * (aT2 + w * (aT4 + w * (aT6 + w * (aT8 + w * aT10)))));
    float s2 = w * (aT1 + w * (aT3 + w * (aT5 + w * (aT7 + w * aT9))));
    if (id < 0) return x - x * (s1 + s2);
    float r;
    if      (id == 0) r = atanhi0 - ((x * (s1 + s2) - atanlo0) - x);
    else if (id == 1) r = atanhi1 - ((x * (s1 + s2) - atanlo1) - x);
    else if (id == 2) r = atanhi2 - ((x * (s1 + s2) - atanlo2) - x);
    else              r = atanhi3 - ((x * (s1 + s2) - atanlo3) - x);
    return (hx < 0) ? -r : r;
}

// ---------------- fdlibm float atan2 (glibc e_atan2f.c), bit-exact port (branchy) ----------------
__device__ __forceinline__ float atan2f_fdlibm(float y, float x) {
#pragma clang fp contract(off)
    const float tiny = 1.0e-30f;
    const float pi_o_4 = 7.8539818525e-01f;
    const float pi_o_2 = 1.5707963705e+00f;
    const float pi     = 3.1415927410e+00f;
    const float pi_lo  = -8.7422776573e-08f;

    int hx = __float_as_int(x), hy = __float_as_int(y);
    int ix = hx & 0x7fffffff, iy = hy & 0x7fffffff;
    if (ix > 0x7f800000 || iy > 0x7f800000) return x + y;
    if (hx == 0x3f800000) return atanf_fdlibm(y);
    int m = ((hy >> 31) & 1) | ((hx >> 30) & 2);

    if (iy == 0) {
        switch (m) {
            case 0:
            case 1:  return y;
            case 2:  return  pi + tiny;
            default: return -pi - tiny;
        }
    }
    if (ix == 0) return (hy < 0) ? (-pi_o_2 - tiny) : (pi_o_2 + tiny);
    if (ix == 0x7f800000) {
        if (iy == 0x7f800000) {
            switch (m) {
                case 0:  return  pi_o_4 + tiny;
                case 1:  return -pi_o_4 - tiny;
                case 2:  return  3.0f * pi_o_4 + tiny;
                default: return -3.0f * pi_o_4 - tiny;
            }
        } else {
            switch (m) {
                case 0:  return  0.0f;
                case 1:  return -0.0f;
                case 2:  return  pi + tiny;
                default: return -pi - tiny;
            }
        }
    }
    if (iy == 0x7f800000) return (hy < 0) ? (-pi_o_2 - tiny) : (pi_o_2 + tiny);

    int k = (iy - ix) >> 23;
    float z;
    int mm = m;
    if (k > 26)                    { z = pi_o_2 + 0.5f * pi_lo; mm &= 1; }
    else if (hx < 0 && k < -26)    { z = 0.0f; }
    else                           { z = atanf_fdlibm(fabsf(y / x)); }

    switch (mm) {
        case 0:  return z;
        case 1:  return -z;
        case 2:  return pi - (z - pi_lo);
        default: return (z - pi_lo) - pi;
    }
}

__device__ __forceinline__ int bin8(float gy, float gx) {
#pragma clang fp contract(off)
    float th = atan2f_fdlibm(gy, gx);
    float t  = th + 3.14159274101257324f;
    float u  = t / 6.28318548202514648f;
    u = u * 8.0f;
    return ((int)u) & 7;
}

// ---------------- branch-free bit-exact bin (select-chains, one division in atan core) ----------
__device__ __forceinline__ int bin8_bf(float gy, float gx) {
#pragma clang fp contract(off)
    const float aT0 = 3.3333334327e-01f, aT1 = -2.0000000298e-01f, aT2 = 1.4285714924e-01f,
                aT3 = -1.1111110449e-01f, aT4 = 9.0908870101e-02f, aT5 = -7.6918758452e-02f,
                aT6 = 6.6610731184e-02f, aT7 = -5.8335702866e-02f, aT8 = 4.9768779427e-02f,
                aT9 = -3.6531571299e-02f, aT10 = 1.6285819933e-02f;
    const float pi    = 3.1415927410e+00f;
    const float pi_lo = -8.7422776573e-08f;
    const float pio2  = 1.5707963705e+00f;

    int hx = __float_as_int(gx), hy = __float_as_int(gy);
    int ix = hx & 0x7fffffff,   iy = hy & 0x7fffffff;
    int m  = ((hy >> 31) & 1) | ((hx >> 30) & 2);

    float q  = fabsf(gy / gx);
    int   iq = __float_as_int(q);

    bool lt04375 = iq < 0x3ee00000;
    bool lt06875 = iq < 0x3f300000;
    bool lt11875 = iq < 0x3f980000;
    bool lt24375 = iq < 0x401c0000;

    float n0 = 2.0f * q - 1.0f, d0 = 2.0f + q;
    float n1 = q - 1.0f,        d1 = q + 1.0f;
    float n2 = q - 1.5f,        d2 = 1.0f + 1.5f * q;
    float num = lt04375 ? q    : lt06875 ? n0 : lt11875 ? n1 : lt24375 ? n2 : -1.0f;
    float den = lt04375 ? 1.0f : lt06875 ? d0 : lt11875 ? d1 : lt24375 ? d2 : q;
    float hi  = lt06875 ? 4.6364760399e-01f : lt11875 ? 7.8539812565e-01f
              : lt24375 ? 9.8279368877e-01f : 1.5707962513e+00f;
    float lo  = lt06875 ? 5.0121582440e-09f : lt11875 ? 3.7748947079e-08f
              : lt24375 ? 3.4473217170e-08f : 7.5497894159e-08f;

    float a  = num / den;
    float z2 = a * a;
    float w2 = z2 * z2;
    float s1 = z2 * (aT0 + w2 * (aT2 + w2 * (aT4 + w2 * (aT6 + w2 * (aT8 + w2 * aT10)))));
    float s2 = w2 * (aT1 + w2 * (aT3 + w2 * (aT5 + w2 * (aT7 + w2 * aT9))));
    float S  = s1 + s2;
    float resm1 = a - a * S;
    float resid = hi - ((a * S - lo) - a);
    float zr = lt04375 ? resm1 : resid;
    zr = (iq >= 0x4c800000) ? (1.5707962513e+00f + 7.5497894159e-08f) : zr;

    int  k    = (iy - ix) >> 23;
    bool kbig = k > 26;
    float z   = kbig ? (pio2 + 0.5f * pi_lo) : zr;
    z = (hx < 0 && k < -26) ? 0.0f : z;
    int mm = kbig ? (m & 1) : m;

    float w  = z - pi_lo;
    float r2 = pi - w;
    float r3 = w - pi;
    float res = (mm == 0) ? z : (mm == 1) ? -z : (mm == 2) ? r2 : r3;
    res = (ix == 0) ? ((hy < 0) ? -pio2 : pio2) : res;
    float piy = (m == 2) ? pi : (m == 3) ? -pi : gy;
    res = (iy == 0) ? piy : res;

    float t = res + 3.14159274101257324f;
    float u = t / 6.28318548202514648f;
    u = u * 8.0f;
    return ((int)u) & 7;
}

__device__ __forceinline__ unsigned rne_bf16_bits(float f) {
    unsigned u = __float_as_uint(f);
    return (u + 0x7fffu + ((u >> 16) & 1u)) >> 16;
}

// ================= stage 1: per-pixel bins, 16 rows per block =================
__global__ __launch_bounds__(256)
void bin_kernel2(const float* __restrict__ x, unsigned* __restrict__ pwg) {
    __shared__ float rs[18][260];
    const int w   = threadIdx.x;
    const int r0  = blockIdx.x << 4;
    const int img = blockIdx.y;      // b*64 + c
    const float* xim = x + ((size_t)img << 16);
    #pragma unroll
    for (int r = 0; r < 18; ++r) {
        int gh = r0 + r - 1;
        rs[r][w + 1] = ((unsigned)gh < 256u) ? xim[(gh << 8) + w] : 0.f;
    }
    if (w < 18) { rs[w][0] = 0.f; rs[w][257] = 0.f; }
    __syncthreads();
    unsigned* orow = pwg + ((size_t)img << 16) + (r0 << 8) + w;
    for (int rr = 0; rr < 16; ++rr) {
        int q; unsigned hv;
        {
#pragma clang fp contract(off)
            float a0 = rs[rr][w],     a1 = rs[rr][w + 1],     a2 = rs[rr][w + 2];
            float m0 = rs[rr + 1][w],                         m2 = rs[rr + 1][w + 2];
            float z0 = rs[rr + 2][w], z1 = rs[rr + 2][w + 1], z2 = rs[rr + 2][w + 2];
            float gx = ((((a0 - a2) + 2.0f * m0) - 2.0f * m2) + z0) - z2;
            float gy = ((((a0 + 2.0f * a1) + a2) - z0) - 2.0f * z1) - z2;
            q  = bin8_bf(gy, gx);
            hv = rne_bf16_bits(rs[rr + 1][w + 1]);
        }
        orow[rr << 8] = (hv << 16) | (unsigned)q;
    }
}

// ================= stage 1b: weights -> [c][t10][o64][k8] bf16 (t=9 zero pad) ===========
__global__ void prep_w2(const float* __restrict__ Wg, short* __restrict__ wsw) {
    int tid = blockIdx.x * 256 + threadIdx.x;
    if (tid >= 4096) return;
    int c = tid >> 6, o = tid & 63;
    for (int t = 0; t < 9; ++t)
        #pragma unroll
        for (int k = 0; k < 8; ++k)
            wsw[((((c * 10 + t) << 6) + o) << 3) + k] =
                (short)rne_bf16_bits(Wg[(((k << 6) + o) * 64 + c) * 9 + t]);
    #pragma unroll
    for (int k = 0; k < 8; ++k)
        wsw[((((c * 10 + 9) << 6) + o) << 3) + k] = 0;
}

// one-hot expansion of packed (bf16<<16|q) into 8 bf16 K-slots (4 words)
__device__ __forceinline__ void build_oh(unsigned pv, u32x4* dst) {
    unsigned q  = pv & 7u;
    unsigned hv = (q & 1u) ? (pv & 0xffff0000u) : (pv >> 16);
    unsigned s2 = q >> 1;
    u32x4 oh;
    oh.x = (s2 == 0u) ? hv : 0u;
    oh.y = (s2 == 1u) ? hv : 0u;
    oh.z = (s2 == 2u) ? hv : 0u;
    oh.w = (s2 == 3u) ? hv : 0u;
    *dst = oh;
}

// ================= stage 2: MFMA GEMM; A in registers (dbuf), B one-hot LDS dbuf =========
// A byte offset for lane (h,l31), channel C, step s, half m:
//   ((C*10 + 2s+h)*64 + (m?32:0) + l31) * 16  =  C*10240 + h*1024 + l31*16 + s*2048 + m*512
#define ALOAD(DST, CC) do {                                                          \
    const char* b_ = (const char*)wsw + (size_t)(CC) * 10240 + abase;                \
    DST[0] = *(const u32x4*)(b_ + 0);    DST[1] = *(const u32x4*)(b_ + 512);         \
    DST[2] = *(const u32x4*)(b_ + 2048); DST[3] = *(const u32x4*)(b_ + 2560);        \
    DST[4] = *(const u32x4*)(b_ + 4096); DST[5] = *(const u32x4*)(b_ + 4608);        \
    DST[6] = *(const u32x4*)(b_ + 6144); DST[7] = *(const u32x4*)(b_ + 6656);        \
    DST[8] = *(const u32x4*)(b_ + 8192); DST[9] = *(const u32x4*)(b_ + 8704);        \
} while (0)

#define CBODY(C, CUR, NXT) do {                                                      \
    const int  cb_ = (C) & 1, nb_ = cb_ ^ 1;                                         \
    const bool more_ = (C) < 63;                                                     \
    unsigned pv0_ = 0, pv1_ = 0;                                                     \
    if (more_) {                                                                     \
        ALOAD(NXT, (C) + 1);                                                         \
        const unsigned* pimg_ = pwg + ((size_t)(bb * 64 + (C) + 1) << 16);           \
        { int gh_ = h0 + r0_ - 1, gw_ = w0c + c0_ - 1;                               \
          if ((unsigned)gh_ < 256u && (unsigned)gw_ < 256u)                          \
              pv0_ = pimg_[(gh_ << 8) + gw_]; }                                      \
        if (tid < 84) { int gh_ = h0 + r1_ - 1, gw_ = w0c + c1_ - 1;                 \
          if ((unsigned)gh_ < 256u && (unsigned)gw_ < 256u)                          \
              pv1_ = pimg_[(gh_ << 8) + gw_]; }                                      \
    }                                                                                \
    const u32x4* pb = &pwx[cb_][0];                                                  \
    _Pragma("unroll")                                                                \
    for (int s = 0; s < 5; ++s) {                                                    \
        short8 a0_ = __builtin_bit_cast(short8, CUR[2 * s]);                         \
        short8 a1_ = __builtin_bit_cast(short8, CUR[2 * s + 1]);                     \
        __builtin_amdgcn_s_setprio(1);                                               \
        _Pragma("unroll")                                                            \
        for (int nf = 0; nf < 2; ++nf) {                                             \
            int py_ = (wave << 1) + nf;                                              \
            short8 bf_ = __builtin_bit_cast(short8,                                  \
                             pb[(py_ + rro[s]) * 36 + l31 + c2o[s]]);                \
            acc[0][nf] = __builtin_amdgcn_mfma_f32_32x32x16_bf16(a0_, bf_, acc[0][nf], 0, 0, 0); \
            acc[1][nf] = __builtin_amdgcn_mfma_f32_32x32x16_bf16(a1_, bf_, acc[1][nf], 0, 0, 0); \
        }                                                                            \
        __builtin_amdgcn_s_setprio(0);                                               \
    }                                                                                \
    if (more_) {                                                                     \
        build_oh(pv0_, &pwx[nb_][r0_ * 36 + c0_]);                                   \
        if (tid < 84) build_oh(pv1_, &pwx[nb_][r1_ * 36 + c1_]);                     \
    }                                                                                \
    __syncthreads();                                                                 \
} while (0)

__global__ __launch_bounds__(256, 3)
void dirconv_mfma5(const unsigned* __restrict__ pwg,
                   const short*    __restrict__ wsw,
                   const float*    __restrict__ bg,
                   float*          __restrict__ out) {
    __shared__ u32x4 pwx[2][360];   // 10 rows x 36 pitch (34 used): per-pixel one-hot
    __shared__ float bsum[64];

    const int tid  = threadIdx.x;
    const int wave = tid >> 6;
    const int lane = tid & 63;
    const int h    = lane >> 5;
    const int l31  = lane & 31;
    const int bb   = blockIdx.z;
    const int h0   = blockIdx.y * TH;
    const int w0c  = blockIdx.x * TW;

    if (tid < 64) {
        float s = 0.f;
        #pragma unroll
        for (int k = 0; k < 8; ++k) s += bg[k * 64 + tid];
        bsum[tid] = s;
    }

    f32x16 acc[2][2];
    #pragma unroll
    for (int i = 0; i < 2; ++i)
        #pragma unroll
        for (int j = 0; j < 2; ++j)
            acc[i][j] = (f32x16)0.f;

    // per-lane tap geometry; t=9 pad -> A slice zeroed in wsw, B read clamped
    int rro[5], c2o[5];
    #pragma unroll
    for (int s = 0; s < 5; ++s) {
        int t = 2 * s + h;
        int t3 = t / 3;
        rro[s] = (t <= 8) ? t3 : 0;
        c2o[s] = (t <= 8) ? (t - t3 * 3) : 0;
    }

    const int abase = h * 1024 + l31 * 16;
    const int r0_ = tid / 34, c0_ = tid - r0_ * 34;
    const int i1_ = tid + 256;
    const int r1_ = i1_ / 34, c1_ = i1_ - r1_ * 34;

    u32x4 Aa[10], Ab[10];

    // ---- prologue: A(c=0) to regs, B(c=0) one-hots to pwx[0] ----
    {
        ALOAD(Aa, 0);
        const unsigned* pimg = pwg + ((size_t)(bb * 64) << 16);
        {
            int gh = h0 + r0_ - 1, gw = w0c + c0_ - 1;
            unsigned pv = 0;
            if ((unsigned)gh < 256u && (unsigned)gw < 256u) pv = pimg[(gh << 8) + gw];
            build_oh(pv, &pwx[0][r0_ * 36 + c0_]);
        }
        if (tid < 84) {
            int gh = h0 + r1_ - 1, gw = w0c + c1_ - 1;
            unsigned pv = 0;
            if ((unsigned)gh < 256u && (unsigned)gw < 256u) pv = pimg[(gh << 8) + gw];
            build_oh(pv, &pwx[0][r1_ * 36 + c1_]);
        }
    }
    __syncthreads();

    for (int c2 = 0; c2 < 64; c2 += 2) {
        CBODY(c2,     Aa, Ab);
        CBODY(c2 + 1, Ab, Aa);
    }

    // ---- epilogue: C/D layout col=lane&31 (pixel), row=(reg&3)+8*(reg>>2)+4*(lane>>5) (o) ----
    float* ob = out + ((size_t)bb << 22);
    #pragma unroll
    for (int mf = 0; mf < 2; ++mf)
        #pragma unroll
        for (int nf = 0; nf < 2; ++nf) {
            int py = (wave << 1) + nf;
            #pragma unroll
            for (int reg = 0; reg < 16; ++reg) {
                int o = mf * 32 + (reg & 3) + 8 * (reg >> 2) + 4 * h;
                ob[((size_t)o << 16) + ((h0 + py) << 8) + (w0c + l31)] =
                    (acc[mf][nf][reg] + bsum[o]) * 0.125f;
            }
        }
}

// ================= fallback: fused kernel (branchy fdlibm, proven) =================
__global__ __launch_bounds__(256, 2)
void dirconv_fb(const float* __restrict__ x,
                const float* __restrict__ Wg,
                const float* __restrict__ bg,
                float* __restrict__ out) {
    __shared__ float    xs[20 * 37];
    __shared__ unsigned pw[18 * 36];
    __shared__ short    wl[64][128];
    __shared__ float    bsum[64];

    const int tid  = threadIdx.x;
    const int wave = tid >> 6;
    const int lane = tid & 63;
    const int h    = lane >> 5;
    const int l31  = lane & 31;
    const int bb   = blockIdx.z;
    const int h0   = blockIdx.y * 16;
    const int w0   = blockIdx.x * 32;

    if (tid < 64) {
        float s = 0.f;
        #pragma unroll
        for (int k = 0; k < 8; ++k) s += bg[k * 64 + tid];
        bsum[tid] = s;
    }

    f32x16 acc[2][4];
    #pragma unroll
    for (int i = 0; i < 2; ++i)
        #pragma unroll
        for (int j = 0; j < 4; ++j)
            acc[i][j] = (f32x16)0.f;

    const int swz0 = l31 & 7;

    for (int c = 0; c < 64; ++c) {
        __syncthreads();
        const float* xc = x + ((size_t)(bb * 64 + c) << 16);
        for (int idx = tid; idx < 720; idx += 256) {
            int r = idx / 36, cc = idx - r * 36;
            int gh = h0 + r - 2, gw = w0 + cc - 2;
            float v = 0.f;
            if ((unsigned)gh < 256u && (unsigned)gw < 256u)
                v = xc[(gh << 8) + gw];
            xs[r * 37 + cc] = v;
        }
        for (int pair = tid; pair < 512; pair += 256) {
            int k = pair >> 6, o = pair & 63;
            const float* g = Wg + ((size_t)((k << 6) + o) * 64 + c) * 9;
            #pragma unroll
            for (int t = 0; t < 9; ++t)
                wl[o][((t ^ (o & 7)) << 3) + k] = (short)rne_bf16_bits(g[t]);
        }
        if (tid < 64) {
            int o = tid;
            #pragma unroll
            for (int e = 0; e < 8; ++e) wl[o][((9 ^ (o & 7)) << 3) + e] = 0;
        }
        __syncthreads();

        for (int idx = tid; idx < 612; idx += 256) {
            int r = idx / 34, cc = idx - r * 34;
            const float* p0 = &xs[r * 37 + cc];
            int q; unsigned hv;
            {
#pragma clang fp contract(off)
                float a0 = p0[0],  a1 = p0[1],  a2 = p0[2];
                float m0 = p0[37],              m2 = p0[39];
                float z0 = p0[74], z1 = p0[75], z2 = p0[76];
                float gx = ((((a0 - a2) + 2.0f * m0) - 2.0f * m2) + z0) - z2;
                float gy = ((((a0 + 2.0f * a1) + a2) - z0) - 2.0f * z1) - z2;
                q  = bin8(gy, gx);
                hv = rne_bf16_bits(p0[38]);
            }
            pw[r * 36 + cc] = (hv << 16) | (unsigned)q;
        }
        __syncthreads();

        #pragma unroll
        for (int s = 0; s < 5; ++s) {
            const int t = 2 * s + h;
            short8 a0 = *(const short8*)&wl[l31     ][(t ^ swz0) << 3];
            short8 a1 = *(const short8*)&wl[32 + l31][(t ^ swz0) << 3];
            const int t3 = t / 3;
            const int dy = t3 - 1, dx = t - t3 * 3 - 1;
            const bool val = (t <= 8);
            #pragma unroll
            for (int nf = 0; nf < 4; ++nf) {
                int py = wave * 4 + nf;
                int rr = val ? (py + 1 + dy) : 0;
                int c2 = val ? (l31 + 1 + dx) : 0;
                unsigned pv = pw[rr * 36 + c2];
                pv = val ? pv : 0u;
                unsigned q   = pv & 7u;
                unsigned hhi = pv & 0xffff0000u;
                unsigned hlo = pv >> 16;
                u32x4 bw;
                bw.x = (q == 0u ? hlo : 0u) | (q == 1u ? hhi : 0u);
                bw.y = (q == 2u ? hlo : 0u) | (q == 3u ? hhi : 0u);
                bw.z = (q == 4u ? hlo : 0u) | (q == 5u ? hhi : 0u);
                bw.w = (q == 6u ? hlo : 0u) | (q == 7u ? hhi : 0u);
                short8 bf = __builtin_bit_cast(short8, bw);
                acc[0][nf] = __builtin_amdgcn_mfma_f32_32x32x16_bf16(a0, bf, acc[0][nf], 0, 0, 0);
                acc[1][nf] = __builtin_amdgcn_mfma_f32_32x32x16_bf16(a1, bf, acc[1][nf], 0, 0, 0);
            }
        }
    }

    float* ob = out + ((size_t)bb << 22);
    #pragma unroll
    for (int mf = 0; mf < 2; ++mf)
        #pragma unroll
        for (int nf = 0; nf < 4; ++nf) {
            int py = wave * 4 + nf;
            #pragma unroll
            for (int reg = 0; reg < 16; ++reg) {
                int o = mf * 32 + (reg & 3) + 8 * (reg >> 2) + 4 * h;
                ob[((size_t)o << 16) + ((h0 + py) << 8) + (w0 + l31)] =
                    (acc[mf][nf][reg] + bsum[o]) * 0.125f;
            }
        }
}

extern "C" void kernel_launch(void* const* d_in, const int* in_sizes, int n_in,
                              void* d_out, int out_size, void* d_ws, size_t ws_size,
                              hipStream_t stream) {
    const float* x  = (const float*)d_in[0];
    const float* Wg = (const float*)d_in[1];
    const float* bg = (const float*)d_in[2];
    float* out = (float*)d_out;

    const size_t pw_bytes   = (size_t)8 * 64 * 256 * 256 * 4;   // 134,217,728
    const size_t wsw2_bytes = (size_t)64 * 10 * 64 * 8 * 2;     // 655,360

    if (ws_size >= pw_bytes + wsw2_bytes) {
        unsigned* pwg = (unsigned*)d_ws;
        short*    wsw = (short*)((char*)d_ws + pw_bytes);
        bin_kernel2<<<dim3(16, 512, 1), 256, 0, stream>>>(x, pwg);
        prep_w2<<<16, 256, 0, stream>>>(Wg, wsw);
        dirconv_mfma5<<<dim3(256 / TW, 256 / TH, 8), 256, 0, stream>>>(pwg, wsw, bg, out);
    } else {
        dirconv_fb<<<dim3(8, 16, 8), 256, 0, stream>>>(x, Wg, bg, out);
    }
}

// Round 13
// 361.850 us; speedup vs baseline: 1.1435x; 1.1435x over previous
//
#include <hip/hip_runtime.h>
#include <math.h>

// DirectionalConv, two-stage:
//   bin_kernel3: per-pixel packed (bf16(x)<<16 | q). Bins == octants: interior pixels
//                classified by signs + |gy|vs|gx| (8 ops); near-boundary pixels (T=1e-3)
//                fall back to the bit-exact branch-free fdlibm chain.
//   dirconv_mfma4 (unchanged from R11): masked-K MFMA GEMM at ~97% of the MFMA
//                instruction-throughput floor (288us model / 298us measured).
// Fallback (small ws): proven fused kernel.

#define TH 8
#define TW 32

typedef __attribute__((ext_vector_type(8)))  short    short8;
typedef __attribute__((ext_vector_type(16))) float    f32x16;
typedef __attribute__((ext_vector_type(4)))  unsigned u32x4;

// ---------------- fdlibm float atan (glibc s_atanf.c), bit-exact port (branchy) ----------------
__device__ __forceinline__ float atanf_fdlibm(float x) {
#pragma clang fp contract(off)
    const float atanhi0 = 4.6364760399e-01f, atanhi1 = 7.8539812565e-01f,
                atanhi2 = 9.8279368877e-01f, atanhi3 = 1.5707962513e+00f;
    const float atanlo0 = 5.0121582440e-09f, atanlo1 = 3.7748947079e-08f,
                atanlo2 = 3.4473217170e-08f, atanlo3 = 7.5497894159e-08f;
    const float aT0 = 3.3333334327e-01f, aT1 = -2.0000000298e-01f, aT2 = 1.4285714924e-01f,
                aT3 = -1.1111110449e-01f, aT4 = 9.0908870101e-02f, aT5 = -7.6918758452e-02f,
                aT6 = 6.6610731184e-02f, aT7 = -5.8335702866e-02f, aT8 = 4.9768779427e-02f,
                aT9 = -3.6531571299e-02f, aT10 = 1.6285819933e-02f;

    int hx = __float_as_int(x);
    int ix = hx & 0x7fffffff;
    int id;
    if (ix >= 0x4c800000) {
        if (ix > 0x7f800000) return x + x;
        return (hx > 0) ? (atanhi3 + atanlo3) : (-atanhi3 - atanlo3);
    }
    if (ix < 0x3ee00000) {
        if (ix < 0x31000000) return x;
        id = -1;
    } else {
        x = fabsf(x);
        if (ix < 0x3f980000) {
            if (ix < 0x3f300000) { id = 0; x = (2.0f * x - 1.0f) / (2.0f + x); }
            else                 { id = 1; x = (x - 1.0f) / (x + 1.0f); }
        } else {
            if (ix < 0x401c0000) { id = 2; x = (x - 1.5f) / (1.0f + 1.5f * x); }
            else                 { id = 3; x = -1.0f / x; }
        }
    }
    float z = x * x;
    float w = z * z;
    float s1 = z * (aT0 + w * (aT2 + w * (aT4 + w * (aT6 + w * (aT8 + w * aT10)))));
    float s2 = w * (aT1 + w * (aT3 + w * (aT5 + w * (aT7 + w * aT9))));
    if (id < 0) return x - x * (s1 + s2);
    float r;
    if      (id == 0) r = atanhi0 - ((x * (s1 + s2) - atanlo0) - x);
    else if (id == 1) r = atanhi1 - ((x * (s1 + s2) - atanlo1) - x);
    else if (id == 2) r = atanhi2 - ((x * (s1 + s2) - atanlo2) - x);
    else              r = atanhi3 - ((x * (s1 + s2) - atanlo3) - x);
    return (hx < 0) ? -r : r;
}

// ---------------- fdlibm float atan2 (glibc e_atan2f.c), bit-exact port (branchy) ----------------
__device__ __forceinline__ float atan2f_fdlibm(float y, float x) {
#pragma clang fp contract(off)
    const float tiny = 1.0e-30f;
    const float pi_o_4 = 7.8539818525e-01f;
    const float pi_o_2 = 1.5707963705e+00f;
    const float pi     = 3.1415927410e+00f;
    const float pi_lo  = -8.7422776573e-08f;

    int hx = __float_as_int(x), hy = __float_as_int(y);
    int ix = hx & 0x7fffffff, iy = hy & 0x7fffffff;
    if (ix > 0x7f800000 || iy > 0x7f800000) return x + y;
    if (hx == 0x3f800000) return atanf_fdlibm(y);
    int m = ((hy >> 31) & 1) | ((hx >> 30) & 2);

    if (iy == 0) {
        switch (m) {
            case 0:
            case 1:  return y;
            case 2:  return  pi + tiny;
            default: return -pi - tiny;
        }
    }
    if (ix == 0) return (hy < 0) ? (-pi_o_2 - tiny) : (pi_o_2 + tiny);
    if (ix == 0x7f800000) {
        if (iy == 0x7f800000) {
            switch (m) {
                case 0:  return  pi_o_4 + tiny;
                case 1:  return -pi_o_4 - tiny;
                case 2:  return  3.0f * pi_o_4 + tiny;
                default: return -3.0f * pi_o_4 - tiny;
            }
        } else {
            switch (m) {
                case 0:  return  0.0f;
                case 1:  return -0.0f;
                case 2:  return  pi + tiny;
                default: return -pi - tiny;
            }
        }
    }
    if (iy == 0x7f800000) return (hy < 0) ? (-pi_o_2 - tiny) : (pi_o_2 + tiny);

    int k = (iy - ix) >> 23;
    float z;
    int mm = m;
    if (k > 26)                    { z = pi_o_2 + 0.5f * pi_lo; mm &= 1; }
    else if (hx < 0 && k < -26)    { z = 0.0f; }
    else                           { z = atanf_fdlibm(fabsf(y / x)); }

    switch (mm) {
        case 0:  return z;
        case 1:  return -z;
        case 2:  return pi - (z - pi_lo);
        default: return (z - pi_lo) - pi;
    }
}

__device__ __forceinline__ int bin8(float gy, float gx) {
#pragma clang fp contract(off)
    float th = atan2f_fdlibm(gy, gx);
    float t  = th + 3.14159274101257324f;
    float u  = t / 6.28318548202514648f;
    u = u * 8.0f;
    return ((int)u) & 7;
}

// ---------------- branch-free bit-exact bin (select-chains, one division) — exact fallback ------
__device__ __forceinline__ int bin8_bf(float gy, float gx) {
#pragma clang fp contract(off)
    const float aT0 = 3.3333334327e-01f, aT1 = -2.0000000298e-01f, aT2 = 1.4285714924e-01f,
                aT3 = -1.1111110449e-01f, aT4 = 9.0908870101e-02f, aT5 = -7.6918758452e-02f,
                aT6 = 6.6610731184e-02f, aT7 = -5.8335702866e-02f, aT8 = 4.9768779427e-02f,
                aT9 = -3.6531571299e-02f, aT10 = 1.6285819933e-02f;
    const float pi    = 3.1415927410e+00f;
    const float pi_lo = -8.7422776573e-08f;
    const float pio2  = 1.5707963705e+00f;

    int hx = __float_as_int(gx), hy = __float_as_int(gy);
    int ix = hx & 0x7fffffff,   iy = hy & 0x7fffffff;
    int m  = ((hy >> 31) & 1) | ((hx >> 30) & 2);

    float q  = fabsf(gy / gx);
    int   iq = __float_as_int(q);

    bool lt04375 = iq < 0x3ee00000;
    bool lt06875 = iq < 0x3f300000;
    bool lt11875 = iq < 0x3f980000;
    bool lt24375 = iq < 0x401c0000;

    float n0 = 2.0f * q - 1.0f, d0 = 2.0f + q;
    float n1 = q - 1.0f,        d1 = q + 1.0f;
    float n2 = q - 1.5f,        d2 = 1.0f + 1.5f * q;
    float num = lt04375 ? q    : lt06875 ? n0 : lt11875 ? n1 : lt24375 ? n2 : -1.0f;
    float den = lt04375 ? 1.0f : lt06875 ? d0 : lt11875 ? d1 : lt24375 ? d2 : q;
    float hi  = lt06875 ? 4.6364760399e-01f : lt11875 ? 7.8539812565e-01f
              : lt24375 ? 9.8279368877e-01f : 1.5707962513e+00f;
    float lo  = lt06875 ? 5.0121582440e-09f : lt11875 ? 3.7748947079e-08f
              : lt24375 ? 3.4473217170e-08f : 7.5497894159e-08f;

    float a  = num / den;
    float z2 = a * a;
    float w2 = z2 * z2;
    float s1 = z2 * (aT0 + w2 * (aT2 + w2 * (aT4 + w2 * (aT6 + w2 * (aT8 + w2 * aT10)))));
    float s2 = w2 * (aT1 + w2 * (aT3 + w2 * (aT5 + w2 * (aT7 + w2 * aT9))));
    float S  = s1 + s2;
    float resm1 = a - a * S;
    float resid = hi - ((a * S - lo) - a);
    float zr = lt04375 ? resm1 : resid;
    zr = (iq >= 0x4c800000) ? (1.5707962513e+00f + 7.5497894159e-08f) : zr;

    int  k    = (iy - ix) >> 23;
    bool kbig = k > 26;
    float z   = kbig ? (pio2 + 0.5f * pi_lo) : zr;
    z = (hx < 0 && k < -26) ? 0.0f : z;
    int mm = kbig ? (m & 1) : m;

    float w  = z - pi_lo;
    float r2 = pi - w;
    float r3 = w - pi;
    float res = (mm == 0) ? z : (mm == 1) ? -z : (mm == 2) ? r2 : r3;
    res = (ix == 0) ? ((hy < 0) ? -pio2 : pio2) : res;
    float piy = (m == 2) ? pi : (m == 3) ? -pi : gy;
    res = (iy == 0) ? piy : res;

    float t = res + 3.14159274101257324f;
    float u = t / 6.28318548202514648f;
    u = u * 8.0f;
    return ((int)u) & 7;
}

// ---------------- fast bin: octant classification + boundary-zone fallback ----------------------
// Bin boundaries are exactly the octant boundaries (tan = {0, +-1, inf}). Interior pixels:
// bin from (sign gx, sign gy, |gy|>|gx|). Pixels within T=1e-3 (tan-space, relative) of a
// boundary — where the reference's f32 rounding decides the side — use the exact chain.
// Chain error is ~2e-6 rad, so T gives >250x margin. Degenerate (gx=0 / gy=0 / both) cases
// land in the zone and hit the exact path.
__device__ __forceinline__ int bin8_fast(float gy, float gx) {
    float ax = fabsf(gx), ay = fabsf(gy);
    float mx = fmaxf(ax, ay);
    bool nb = (ay <= 1e-3f * ax) || (ax <= 1e-3f * ay) || (fabsf(ax - ay) <= 1e-3f * mx);
    if (__builtin_expect(nb, 0)) return bin8_bf(gy, gx);
    int sx = (__float_as_int(gx) >> 31) & 1;
    int sy = (__float_as_int(gy) >> 31) & 1;
    int d  = ay > ax;
    int s  = sy ? (sx ^ 1) : sx;
    int base = sy ? 0 : 4;
    return base + ((s << 1) | (s ^ d));
}

__device__ __forceinline__ unsigned rne_bf16_bits(float f) {
    unsigned u = __float_as_uint(f);
    return (u + 0x7fffu + ((u >> 16) & 1u)) >> 16;
}

// ================= stage 1: per-pixel bins, 16 rows per block =================
__global__ __launch_bounds__(256)
void bin_kernel3(const float* __restrict__ x, unsigned* __restrict__ pwg) {
    __shared__ float rs[18][260];
    const int w   = threadIdx.x;
    const int r0  = blockIdx.x << 4;
    const int img = blockIdx.y;      // b*64 + c
    const float* xim = x + ((size_t)img << 16);
    #pragma unroll
    for (int r = 0; r < 18; ++r) {
        int gh = r0 + r - 1;
        rs[r][w + 1] = ((unsigned)gh < 256u) ? xim[(gh << 8) + w] : 0.f;
    }
    if (w < 18) { rs[w][0] = 0.f; rs[w][257] = 0.f; }
    __syncthreads();
    unsigned* orow = pwg + ((size_t)img << 16) + (r0 << 8) + w;
    for (int rr = 0; rr < 16; ++rr) {
        int q; unsigned hv;
        {
#pragma clang fp contract(off)
            float a0 = rs[rr][w],     a1 = rs[rr][w + 1],     a2 = rs[rr][w + 2];
            float m0 = rs[rr + 1][w],                         m2 = rs[rr + 1][w + 2];
            float z0 = rs[rr + 2][w], z1 = rs[rr + 2][w + 1], z2 = rs[rr + 2][w + 2];
            float gx = ((((a0 - a2) + 2.0f * m0) - 2.0f * m2) + z0) - z2;
            float gy = ((((a0 + 2.0f * a1) + a2) - z0) - 2.0f * z1) - z2;
            q  = bin8_fast(gy, gx);
            hv = rne_bf16_bits(rs[rr + 1][w + 1]);
        }
        orow[rr << 8] = (hv << 16) | (unsigned)q;
    }
}

// ================= stage 1b: weights -> [c][t10][o64][k8] bf16 (t=9 zero pad) ===========
__global__ void prep_w2(const float* __restrict__ Wg, short* __restrict__ wsw) {
    int tid = blockIdx.x * 256 + threadIdx.x;
    if (tid >= 4096) return;
    int c = tid >> 6, o = tid & 63;
    for (int t = 0; t < 9; ++t)
        #pragma unroll
        for (int k = 0; k < 8; ++k)
            wsw[((((c * 10 + t) << 6) + o) << 3) + k] =
                (short)rne_bf16_bits(Wg[(((k << 6) + o) * 64 + c) * 9 + t]);
    #pragma unroll
    for (int k = 0; k < 8; ++k)
        wsw[((((c * 10 + 9) << 6) + o) << 3) + k] = 0;
}

// one-hot expansion of packed (bf16<<16|q) into 8 bf16 K-slots (4 words)
__device__ __forceinline__ void build_oh(unsigned pv, u32x4* dst) {
    unsigned q  = pv & 7u;
    unsigned hv = (q & 1u) ? (pv & 0xffff0000u) : (pv >> 16);
    unsigned s2 = q >> 1;
    u32x4 oh;
    oh.x = (s2 == 0u) ? hv : 0u;
    oh.y = (s2 == 1u) ? hv : 0u;
    oh.z = (s2 == 2u) ? hv : 0u;
    oh.w = (s2 == 3u) ? hv : 0u;
    *dst = oh;
}

// ================= stage 2: MFMA GEMM, A+B LDS dbuf, full-phase prefetch, 4 blk/CU =======
__global__ __launch_bounds__(256, 4)
void dirconv_mfma4(const unsigned* __restrict__ pwg,
                   const short*    __restrict__ wsw,
                   const float*    __restrict__ bg,
                   float*          __restrict__ out) {
    __shared__ u32x4 pwx[2][360];   // 10 rows x 36 pitch (34 used): per-pixel one-hot
    __shared__ u32x4 wl2[2][640];   // [t10][o64]: A fragments, lane-contiguous
    __shared__ float bsum[64];

    const int tid  = threadIdx.x;
    const int wave = tid >> 6;
    const int lane = tid & 63;
    const int h    = lane >> 5;
    const int l31  = lane & 31;
    const int bb   = blockIdx.z;
    const int h0   = blockIdx.y * TH;
    const int w0c  = blockIdx.x * TW;

    if (tid < 64) {
        float s = 0.f;
        #pragma unroll
        for (int k = 0; k < 8; ++k) s += bg[k * 64 + tid];
        bsum[tid] = s;
    }

    f32x16 acc[2][2];
    #pragma unroll
    for (int i = 0; i < 2; ++i)
        #pragma unroll
        for (int j = 0; j < 2; ++j)
            acc[i][j] = (f32x16)0.f;

    // per-lane tap geometry; t=9 pad -> A slice zeroed in wsw, B read clamped
    int rro[5], c2o[5];
    #pragma unroll
    for (int s = 0; s < 5; ++s) {
        int t = 2 * s + h;
        int t3 = t / 3;
        rro[s] = (t <= 8) ? t3 : 0;
        c2o[s] = (t <= 8) ? (t - t3 * 3) : 0;
    }

    const int r0_ = tid / 34, c0_ = tid - r0_ * 34;
    const int i1_ = tid + 256;
    const int r1_ = i1_ / 34, c1_ = i1_ - r1_ * 34;

    // ---- prologue: stage c = 0 into buffer 0 ----
    {
        const u32x4* wsrc = (const u32x4*)wsw;
        wl2[0][tid]       = wsrc[tid];
        wl2[0][tid + 256] = wsrc[tid + 256];
        if (tid < 128) wl2[0][tid + 512] = wsrc[tid + 512];
        const unsigned* pimg = pwg + ((size_t)(bb * 64) << 16);
        {
            int gh = h0 + r0_ - 1, gw = w0c + c0_ - 1;
            unsigned pv = 0;
            if ((unsigned)gh < 256u && (unsigned)gw < 256u) pv = pimg[(gh << 8) + gw];
            build_oh(pv, &pwx[0][r0_ * 36 + c0_]);
        }
        if (tid < 84) {
            int gh = h0 + r1_ - 1, gw = w0c + c1_ - 1;
            unsigned pv = 0;
            if ((unsigned)gh < 256u && (unsigned)gw < 256u) pv = pimg[(gh << 8) + gw];
            build_oh(pv, &pwx[0][r1_ * 36 + c1_]);
        }
    }
    __syncthreads();

    for (int c = 0; c < 64; ++c) {
        const int cb = c & 1, nb = cb ^ 1;
        const bool more = (c < 63);
        u32x4 wv0 = (u32x4)0u, wv1 = (u32x4)0u, wv2 = (u32x4)0u;
        unsigned pv0 = 0, pv1 = 0;

        if (more) {   // full-phase prefetch: issue now, consume at phase end
            const u32x4* wsrc = (const u32x4*)(wsw + (size_t)(c + 1) * 5120);
            wv0 = wsrc[tid];
            wv1 = wsrc[tid + 256];
            if (tid < 128) wv2 = wsrc[tid + 512];
            const unsigned* pimg = pwg + ((size_t)(bb * 64 + c + 1) << 16);
            {
                int gh = h0 + r0_ - 1, gw = w0c + c0_ - 1;
                if ((unsigned)gh < 256u && (unsigned)gw < 256u) pv0 = pimg[(gh << 8) + gw];
            }
            if (tid < 84) {
                int gh = h0 + r1_ - 1, gw = w0c + c1_ - 1;
                if ((unsigned)gh < 256u && (unsigned)gw < 256u) pv1 = pimg[(gh << 8) + gw];
            }
        }

        // ---- MFMA from buffer cb: 20 MFMAs/wave, pure ds_read_b128 + mfma ----
        const u32x4* pb = &pwx[cb][0];
        const u32x4* wb = &wl2[cb][0];
        #pragma unroll
        for (int s = 0; s < 5; ++s) {
            const int t = 2 * s + h;
            short8 a0 = __builtin_bit_cast(short8, wb[t * 64 + l31]);
            short8 a1 = __builtin_bit_cast(short8, wb[t * 64 + 32 + l31]);
            __builtin_amdgcn_s_setprio(1);
            #pragma unroll
            for (int nf = 0; nf < 2; ++nf) {
                int py = (wave << 1) + nf;
                short8 bf = __builtin_bit_cast(short8,
                                pb[(py + rro[s]) * 36 + l31 + c2o[s]]);
                acc[0][nf] = __builtin_amdgcn_mfma_f32_32x32x16_bf16(a0, bf, acc[0][nf], 0, 0, 0);
                acc[1][nf] = __builtin_amdgcn_mfma_f32_32x32x16_bf16(a1, bf, acc[1][nf], 0, 0, 0);
            }
            __builtin_amdgcn_s_setprio(0);
        }

        // ---- phase end: write staged c+1 into buffer nb ----
        if (more) {
            wl2[nb][tid]       = wv0;
            wl2[nb][tid + 256] = wv1;
            if (tid < 128) wl2[nb][tid + 512] = wv2;
            build_oh(pv0, &pwx[nb][r0_ * 36 + c0_]);
            if (tid < 84) build_oh(pv1, &pwx[nb][r1_ * 36 + c1_]);
        }
        __syncthreads();
    }

    // ---- epilogue: C/D layout col=lane&31 (pixel), row=(reg&3)+8*(reg>>2)+4*(lane>>5) (o) ----
    float* ob = out + ((size_t)bb << 22);
    #pragma unroll
    for (int mf = 0; mf < 2; ++mf)
        #pragma unroll
        for (int nf = 0; nf < 2; ++nf) {
            int py = (wave << 1) + nf;
            #pragma unroll
            for (int reg = 0; reg < 16; ++reg) {
                int o = mf * 32 + (reg & 3) + 8 * (reg >> 2) + 4 * h;
                ob[((size_t)o << 16) + ((h0 + py) << 8) + (w0c + l31)] =
                    (acc[mf][nf][reg] + bsum[o]) * 0.125f;
            }
        }
}

// ================= fallback: fused kernel (branchy fdlibm, proven) =================
__global__ __launch_bounds__(256, 2)
void dirconv_fb(const float* __restrict__ x,
                const float* __restrict__ Wg,
                const float* __restrict__ bg,
                float* __restrict__ out) {
    __shared__ float    xs[20 * 37];
    __shared__ unsigned pw[18 * 36];
    __shared__ short    wl[64][128];
    __shared__ float    bsum[64];

    const int tid  = threadIdx.x;
    const int wave = tid >> 6;
    const int lane = tid & 63;
    const int h    = lane >> 5;
    const int l31  = lane & 31;
    const int bb   = blockIdx.z;
    const int h0   = blockIdx.y * 16;
    const int w0   = blockIdx.x * 32;

    if (tid < 64) {
        float s = 0.f;
        #pragma unroll
        for (int k = 0; k < 8; ++k) s += bg[k * 64 + tid];
        bsum[tid] = s;
    }

    f32x16 acc[2][4];
    #pragma unroll
    for (int i = 0; i < 2; ++i)
        #pragma unroll
        for (int j = 0; j < 4; ++j)
            acc[i][j] = (f32x16)0.f;

    const int swz0 = l31 & 7;

    for (int c = 0; c < 64; ++c) {
        __syncthreads();
        const float* xc = x + ((size_t)(bb * 64 + c) << 16);
        for (int idx = tid; idx < 720; idx += 256) {
            int r = idx / 36, cc = idx - r * 36;
            int gh = h0 + r - 2, gw = w0 + cc - 2;
            float v = 0.f;
            if ((unsigned)gh < 256u && (unsigned)gw < 256u)
                v = xc[(gh << 8) + gw];
            xs[r * 37 + cc] = v;
        }
        for (int pair = tid; pair < 512; pair += 256) {
            int k = pair >> 6, o = pair & 63;
            const float* g = Wg + ((size_t)((k << 6) + o) * 64 + c) * 9;
            #pragma unroll
            for (int t = 0; t < 9; ++t)
                wl[o][((t ^ (o & 7)) << 3) + k] = (short)rne_bf16_bits(g[t]);
        }
        if (tid < 64) {
            int o = tid;
            #pragma unroll
            for (int e = 0; e < 8; ++e) wl[o][((9 ^ (o & 7)) << 3) + e] = 0;
        }
        __syncthreads();

        for (int idx = tid; idx < 612; idx += 256) {
            int r = idx / 34, cc = idx - r * 34;
            const float* p0 = &xs[r * 37 + cc];
            int q; unsigned hv;
            {
#pragma clang fp contract(off)
                float a0 = p0[0],  a1 = p0[1],  a2 = p0[2];
                float m0 = p0[37],              m2 = p0[39];
                float z0 = p0[74], z1 = p0[75], z2 = p0[76];
                float gx = ((((a0 - a2) + 2.0f * m0) - 2.0f * m2) + z0) - z2;
                float gy = ((((a0 + 2.0f * a1) + a2) - z0) - 2.0f * z1) - z2;
                q  = bin8(gy, gx);
                hv = rne_bf16_bits(p0[38]);
            }
            pw[r * 36 + cc] = (hv << 16) | (unsigned)q;
        }
        __syncthreads();

        #pragma unroll
        for (int s = 0; s < 5; ++s) {
            const int t = 2 * s + h;
            short8 a0 = *(const short8*)&wl[l31     ][(t ^ swz0) << 3];
            short8 a1 = *(const short8*)&wl[32 + l31][(t ^ swz0) << 3];
            const int t3 = t / 3;
            const int dy = t3 - 1, dx = t - t3 * 3 - 1;
            const bool val = (t <= 8);
            #pragma unroll
            for (int nf = 0; nf < 4; ++nf) {
                int py = wave * 4 + nf;
                int rr = val ? (py + 1 + dy) : 0;
                int c2 = val ? (l31 + 1 + dx) : 0;
                unsigned pv = pw[rr * 36 + c2];
                pv = val ? pv : 0u;
                unsigned q   = pv & 7u;
                unsigned hhi = pv & 0xffff0000u;
                unsigned hlo = pv >> 16;
                u32x4 bw;
                bw.x = (q == 0u ? hlo : 0u) | (q == 1u ? hhi : 0u);
                bw.y = (q == 2u ? hlo : 0u) | (q == 3u ? hhi : 0u);
                bw.z = (q == 4u ? hlo : 0u) | (q == 5u ? hhi : 0u);
                bw.w = (q == 6u ? hlo : 0u) | (q == 7u ? hhi : 0u);
                short8 bf = __builtin_bit_cast(short8, bw);
                acc[0][nf] = __builtin_amdgcn_mfma_f32_32x32x16_bf16(a0, bf, acc[0][nf], 0, 0, 0);
                acc[1][nf] = __builtin_amdgcn_mfma_f32_32x32x16_bf16(a1, bf, acc[1][nf], 0, 0, 0);
            }
        }
    }

    float* ob = out + ((size_t)bb << 22);
    #pragma unroll
    for (int mf = 0; mf < 2; ++mf)
        #pragma unroll
        for (int nf = 0; nf < 4; ++nf) {
            int py = wave * 4 + nf;
            #pragma unroll
            for (int reg = 0; reg < 16; ++reg) {
                int o = mf * 32 + (reg & 3) + 8 * (reg >> 2) + 4 * h;
                ob[((size_t)o << 16) + ((h0 + py) << 8) + (w0 + l31)] =
                    (acc[mf][nf][reg] + bsum[o]) * 0.125f;
            }
        }
}

extern "C" void kernel_launch(void* const* d_in, const int* in_sizes, int n_in,
                              void* d_out, int out_size, void* d_ws, size_t ws_size,
                              hipStream_t stream) {
    const float* x  = (const float*)d_in[0];
    const float* Wg = (const float*)d_in[1];
    const float* bg = (const float*)d_in[2];
    float* out = (float*)d_out;

    const size_t pw_bytes   = (size_t)8 * 64 * 256 * 256 * 4;   // 134,217,728
    const size_t wsw2_bytes = (size_t)64 * 10 * 64 * 8 * 2;     // 655,360

    if (ws_size >= pw_bytes + wsw2_bytes) {
        unsigned* pwg = (unsigned*)d_ws;
        short*    wsw = (short*)((char*)d_ws + pw_bytes);
        bin_kernel3<<<dim3(16, 512, 1), 256, 0, stream>>>(x, pwg);
        prep_w2<<<16, 256, 0, stream>>>(Wg, wsw);
        dirconv_mfma4<<<dim3(256 / TW, 256 / TH, 8), 256, 0, stream>>>(pwg, wsw, bg, out);
    } else {
        dirconv_fb<<<dim3(8, 16, 8), 256, 0, stream>>>(x, Wg, bg, out);
    }
}